// Round 4
// baseline (98.814 us; speedup 1.0000x reference)
//
#include <hip/hip_runtime.h>
#include <stdint.h>

// VarifoldKernel: out[b] = sum_{n,m} w1[b,n]*w2[b,m]*exp(-2*||p1-p2||^2)*exp(-f1.f2/2)
// Log-space: term = 2^( dot(U1[n],U2[m]) + la1[n] + la2[m] ),
//   U1 = [2*pos1, feat1] fp16, U2 = [2*L*pos2, -0.5*L*feat2] fp16, L = log2(e)
//   la = log2(w) - 2*L*|pos|^2
// K = 67 padded to 96. fp16 MFMA 16x16x32, fp32 accumulate.
// R4: 2 kernels only. prep zeroes d_out; varifold block-reduces and does one
//     atomicAdd per block (reduce kernel gone). Packed-f32 (v_pk_add_f32)
//     epilogue with 4 independent packed accumulators. Core loop unchanged
//     from R3 (register-persistent B stripe, barrier-free, 1-tile A prefetch).

typedef _Float16 f16;
typedef _Float16 v8h __attribute__((ext_vector_type(8)));
typedef _Float16 h4  __attribute__((ext_vector_type(4)));
typedef float    v4f __attribute__((ext_vector_type(4)));
typedef float    v2f __attribute__((ext_vector_type(2)));

#define L2E 1.4426950408889634f
#define BN 4096
#define KP 96    // padded K (halfs); row = 192 B

// ---------------- prep: fp32 -> fp16 U matrices + log-space row terms ----------------
__global__ __launch_bounds__(256) void prep_kernel(
    const float* __restrict__ pos1, const float* __restrict__ feat1, const float* __restrict__ w1,
    const float* __restrict__ pos2, const float* __restrict__ feat2, const float* __restrict__ w2,
    f16* __restrict__ U1, f16* __restrict__ U2,
    float* __restrict__ la1, float* __restrict__ la2,
    float* __restrict__ out)
{
    int tid  = threadIdx.x;
    if (blockIdx.x == 0 && tid < 4) out[tid] = 0.0f;   // init accumulator for varifold atomics

    int ridx = blockIdx.x * 16 + (tid >> 4);   // 0..32767
    int c    = tid & 15;
    int side = ridx >> 14;                     // 0: side1, 1: side2
    int idx  = ridx & 16383;                   // b*4096 + row

    const float* feat = side ? feat2 : feat1;
    f16* U   = side ? U2 : U1;
    float fs = side ? -0.5f * L2E : 1.0f;

    float4 v = ((const float4*)feat)[idx * 16 + c];
    *(h4*)(U + (long)idx * KP + 4 + c * 4) =
        h4{(f16)(v.x * fs), (f16)(v.y * fs), (f16)(v.z * fs), (f16)(v.w * fs)};

    if (c == 0) {
        const float* pos = side ? pos2 : pos1;
        const float* w   = side ? w2   : w1;
        float* la = side ? la2 : la1;
        float ps  = side ? 2.0f * L2E : 2.0f;
        float p0 = pos[idx*3+0], p1 = pos[idx*3+1], p2 = pos[idx*3+2];
        la[idx] = __builtin_amdgcn_logf(w[idx]) - 2.0f * L2E * (p0*p0 + p1*p1 + p2*p2);
        *(h4*)(U + (long)idx * KP) = h4{(f16)(p0*ps), (f16)(p1*ps), (f16)(p2*ps), (f16)0.0f};
    } else if (c <= 7) {
        *(h4*)(U + (long)idx * KP + 68 + (c - 1) * 4) =
            h4{(f16)0.0f, (f16)0.0f, (f16)0.0f, (f16)0.0f};
    }
}

// ---------------- main: barrier-free core, register-persistent B stripe -------------
// Block = 4 waves. Wave w owns cols [stripe*256 + w*64, +64) for a 256-row chunk.
// B frags + la2 persist in registers; A frags loaded per 16-row tile, 1-tile prefetch.
// Finish: wave shuffle-reduce -> 16B LDS -> one atomicAdd per block into out[b].
__global__ __launch_bounds__(256, 4) void varifold_kernel(
    const f16* __restrict__ U1, const f16* __restrict__ U2,
    const float* __restrict__ la1, const float* __restrict__ la2,
    float* __restrict__ out)
{
    __shared__ float sred[4];
    int tid = threadIdx.x, wave = tid >> 6, lane = tid & 63;
    int stripe = blockIdx.x, nchunk = blockIdx.y, b = blockIdx.z;
    int l15 = lane & 15, quad = lane >> 4;

    long colr = (long)b*BN + stripe*256 + wave*64;   // this wave's first col row-index
    long row0 = (long)b*BN + nchunk*256;             // this block's first row

    // --- persistent B fragments + la2 (registers for whole kernel) ---
    v8h bf[3][4];
    float la2v[4];
    #pragma unroll
    for (int j = 0; j < 4; ++j) {
        const f16* r = U2 + (colr + j*16 + l15) * KP + quad*8;
        bf[0][j] = *(const v8h*)(r);
        bf[1][j] = *(const v8h*)(r + 32);
        bf[2][j] = *(const v8h*)(r + 64);
        la2v[j]  = la2[colr + j*16 + l15];
    }

    const f16* Ab = U1 + (row0 + l15) * KP + quad*8;  // A frag base (+16 rows/tile)
    v8h afc[3], afn[3];
    afc[0] = *(const v8h*)(Ab);
    afc[1] = *(const v8h*)(Ab + 32);
    afc[2] = *(const v8h*)(Ab + 64);

    v2f ps0 = v2f{0.f, 0.f}, ps1 = v2f{0.f, 0.f};
    v2f ps2 = v2f{0.f, 0.f}, ps3 = v2f{0.f, 0.f};

    #pragma unroll 2
    for (int t = 0; t < 16; ++t) {
        // prefetch next tile's A fragments (clamped; last iter re-loads self)
        const f16* An = Ab + (t < 15 ? (t+1) : t) * 16 * KP;
        afn[0] = *(const v8h*)(An);
        afn[1] = *(const v8h*)(An + 32);
        afn[2] = *(const v8h*)(An + 64);

        v4f acc[4];
        #pragma unroll
        for (int j = 0; j < 4; ++j) acc[j] = v4f{0.f, 0.f, 0.f, 0.f};
        #pragma unroll
        for (int k = 0; k < 3; ++k)
            #pragma unroll
            for (int j = 0; j < 4; ++j)
                acc[j] = __builtin_amdgcn_mfma_f32_16x16x32_f16(afc[k], bf[k][j], acc[j], 0, 0, 0);

        // epilogue: C/D layout col=lane&15, row=quad*4+reg. Packed f32 math.
        float4 l1 = *(const float4*)(la1 + row0 + t*16 + quad*4);
        v2f l1a = v2f{l1.x, l1.y}, l1b = v2f{l1.z, l1.w};
        #pragma unroll
        for (int j = 0; j < 4; ++j) {
            v2f la2j = v2f{la2v[j], la2v[j]};
            v2f ta = v2f{acc[j][0], acc[j][1]} + l1a + la2j;   // v_pk_add_f32
            v2f tb = v2f{acc[j][2], acc[j][3]} + l1b + la2j;
            v2f ea = v2f{__builtin_amdgcn_exp2f(ta.x), __builtin_amdgcn_exp2f(ta.y)};
            v2f eb = v2f{__builtin_amdgcn_exp2f(tb.x), __builtin_amdgcn_exp2f(tb.y)};
            if (j == 0)      { ps0 += ea; ps0 += eb; }
            else if (j == 1) { ps1 += ea; ps1 += eb; }
            else if (j == 2) { ps2 += ea; ps2 += eb; }
            else             { ps3 += ea; ps3 += eb; }
        }

        afc[0] = afn[0]; afc[1] = afn[1]; afc[2] = afn[2];
    }

    v2f ps = (ps0 + ps1) + (ps2 + ps3);
    float psum = ps.x + ps.y;

    // --- wave reduce -> LDS -> one atomicAdd per block ---
    #pragma unroll
    for (int off = 32; off > 0; off >>= 1) psum += __shfl_down(psum, off);
    if (lane == 0) sred[wave] = psum;
    __syncthreads();
    if (tid == 0) atomicAdd(out + b, (sred[0] + sred[1]) + (sred[2] + sred[3]));
}

extern "C" void kernel_launch(void* const* d_in, const int* in_sizes, int n_in,
                              void* d_out, int out_size, void* d_ws, size_t ws_size,
                              hipStream_t stream) {
    const float* pos1  = (const float*)d_in[0];
    const float* feat1 = (const float*)d_in[1];
    const float* w1    = (const float*)d_in[2];
    const float* pos2  = (const float*)d_in[3];
    const float* feat2 = (const float*)d_in[4];
    const float* w2    = (const float*)d_in[5];
    float* out = (float*)d_out;

    // workspace layout (6,422,528 B)
    char* ws = (char*)d_ws;
    f16*   U1  = (f16*)(ws);                          // 3,145,728
    f16*   U2  = (f16*)(ws + 3145728);                // 3,145,728
    float* la1 = (float*)(ws + 6291456);              // 65,536
    float* la2 = (float*)(ws + 6291456 + 65536);      // 65,536

    prep_kernel<<<2048, 256, 0, stream>>>(pos1, feat1, w1, pos2, feat2, w2,
                                          U1, U2, la1, la2, out);
    dim3 grid(16, 16, 4);  // (stripe, nchunk, b) — stripe fastest for A-row L2 locality
    varifold_kernel<<<grid, 256, 0, stream>>>(U1, U2, la1, la2, out);
}